// Round 7
// baseline (383.573 us; speedup 1.0000x reference)
//
#include <hip/hip_runtime.h>

typedef __attribute__((ext_vector_type(8))) short short8;
typedef __attribute__((ext_vector_type(4))) float f32x4;
typedef __attribute__((ext_vector_type(4))) unsigned short ushort4v;

// dA2[sn][q] = coefficient of k_q in stage sn's input (zero-padded; row 0 unused)
__device__ __constant__ float dA2[6][6] = {
  {0.f, 0.f, 0.f, 0.f, 0.f, 0.f},
  {0.161f, 0.f, 0.f, 0.f, 0.f, 0.f},
  {-0.008480655492356989f, 0.335480655492357f, 0.f, 0.f, 0.f, 0.f},
  {2.8971530571054935f, -6.359448489975075f, 4.3622954328695815f, 0.f, 0.f, 0.f},
  {5.325864828439257f, -11.748883564062828f, 7.4955393428898365f, -0.09249506636175525f, 0.f, 0.f},
  {5.86145544294642f, -12.92096931784711f, 8.159367898576159f, -0.071584973281401f, -0.028269050394068383f, 0.f}
};
__device__ __constant__ float dC6[6] = {0.f, 0.161f, 0.327f, 0.9f, 0.9800255409045097f, 1.0f};
__device__ __constant__ float dB6v[6] = {0.09646076681806523f, 0.01f, 0.4798896504144996f,
                                         1.379008574103742f, -3.290069515436081f, 2.324710524099774f};

#define NSTEPS 49
#define XS 136   // bf16 activation row stride (272 B = 17*16)

__device__ __forceinline__ unsigned short f2bf(float f) {
    unsigned u = __builtin_bit_cast(unsigned, f);
    u += 0x7fff + ((u >> 16) & 1);
    return (unsigned short)(u >> 16);
}

// 512 blocks x 256 thr (4 waves), M=4 batch rows/block -> 2 BLOCKS/CU (independent
// timelines fill each other's barrier/latency bubbles; that was R5/R6's stall).
// Transposed MFMA: C'[n][m] = sum_k W[n][k] X[m][k]; A = register weights, B = activation
// b128 reads (shared across the wave's two N-tiles), C' gives 4 consecutive neurons
// per lane -> b64 epilogue writes. L1/L2: wave w owns cols [32w,32w+32) (2 tiles);
// L3: cols [16w,16w+16). L3 epilogue keeps k1..k6 and y in registers (fused build).
// Pad rows m=4..15 carry finite garbage, rewritten every phase - never poison real rows.
extern "C" __global__ void __launch_bounds__(256, 2)
node_solve(const float* __restrict__ y0, const float* __restrict__ ts,
           const float* __restrict__ gw0, const float* __restrict__ gb0,
           const float* __restrict__ gw1, const float* __restrict__ gb1,
           const float* __restrict__ gw2, const float* __restrict__ gb2,
           float* __restrict__ out)
{
    __shared__ __align__(16) unsigned short sSI[16 * XS];  // [y' | t | zero pad], K-extent 96
    __shared__ __align__(16) unsigned short sH1[16 * XS];  // K=128
    __shared__ __align__(16) unsigned short sH2[16 * XS];  // K=128

    const int tid  = threadIdx.x;
    const int w    = tid >> 6;
    const int lane = tid & 63;
    const int q    = lane >> 4;
    const int c    = lane & 15;
    const int n12  = 32 * w;    // L1/L2 col base (2 tiles)
    const int n3   = 16 * w;    // L3 col base (1 tile)
    const int row0 = blockIdx.x * 4;

    // ---- zero SI cols 0..95 for all 16 rows (k-pad must be 0) ----
    for (int i = tid; i < 16 * 48; i += 256) {
        int r = i / 48, j = i - r * 48;
        ((int*)sSI)[r * 68 + j] = 0;
    }
    __syncthreads();
    // ---- init SI: rows 0..3 <- y0, time col 64 for all 16 rows ----
    {
        int r = tid >> 6, d = tid & 63;
        sSI[r * XS + d] = f2bf(y0[(size_t)(row0 + r) * 64 + d]);
        if (tid < 16) sSI[tid * XS + 64] = f2bf(ts[0]);
    }

    // ---- weights -> register A-frags ----
    // L1 k-permutation: k<64 -> gw0 col 1+k (y_k); k==64 -> gw0 col 0 (t); k>64 -> 0
    short8 wL1[2][3], wL2[2][4], wL3[4];
    float  bL1[2], bL2[2], bL3;
    #pragma unroll
    for (int t = 0; t < 2; ++t) {
        const int n = n12 + 16 * t + c;
        #pragma unroll
        for (int ks = 0; ks < 3; ++ks) {
            short8 v;
            #pragma unroll
            for (int j = 0; j < 8; ++j) {
                const int k = ks * 32 + q * 8 + j;
                float f = (k < 64) ? gw0[n * 65 + 1 + k] : (k == 64 ? gw0[n * 65] : 0.f);
                v[j] = (short)f2bf(f);
            }
            wL1[t][ks] = v;
        }
        #pragma unroll
        for (int ks = 0; ks < 4; ++ks) {
            short8 v;
            #pragma unroll
            for (int j = 0; j < 8; ++j) v[j] = (short)f2bf(gw1[n * 128 + ks * 32 + q * 8 + j]);
            wL2[t][ks] = v;
        }
        bL1[t] = gb0[n]; bL2[t] = gb1[n];
    }
    {
        const int n = n3 + c;
        #pragma unroll
        for (int ks = 0; ks < 4; ++ks) {
            short8 v;
            #pragma unroll
            for (int j = 0; j < 8; ++j) v[j] = (short)f2bf(gw2[n * 128 + ks * 32 + q * 8 + j]);
            wL3[ks] = v;
        }
        bL3 = gb2[n];
    }

    // ---- persistent ODE state (all lanes; real rows are c<4): row c, dims n3+q*4+r ----
    float sy[4] = {0.f, 0.f, 0.f, 0.f};
    float k0[4], k1[4], k2[4], k3[4], k4[4], k5[4];
    #pragma unroll
    for (int r = 0; r < 4; ++r) { k0[r]=0.f; k1[r]=0.f; k2[r]=0.f; k3[r]=0.f; k4[r]=0.f; k5[r]=0.f; }
    if (c < 4) {
        #pragma unroll
        for (int r = 0; r < 4; ++r)
            sy[r] = y0[(size_t)(row0 + c) * 64 + n3 + q * 4 + r];
    }

    const float ts0 = ts[0];
    const float dtv = ts[1] - ts[0];

    __syncthreads();

    #pragma unroll 1
    for (int step = 0; step < NSTEPS; ++step) {
        const float tstep = ts0 + (float)step * dtv;

        #pragma unroll 1
        for (int s = 0; s < 6; ++s) {
            // ---- P1: L1 (SI K=96 -> H1, relu); 2 N-tiles, shared B-frags ----
            {
                const unsigned short* xb = &sSI[c * XS + q * 8];
                short8 x0 = *(const short8*)(xb);
                short8 x1 = *(const short8*)(xb + 32);
                short8 x2 = *(const short8*)(xb + 64);
                f32x4 a0 = {0.f,0.f,0.f,0.f}, a1 = {0.f,0.f,0.f,0.f};
                a0 = __builtin_amdgcn_mfma_f32_16x16x32_bf16(wL1[0][0], x0, a0, 0, 0, 0);
                a1 = __builtin_amdgcn_mfma_f32_16x16x32_bf16(wL1[1][0], x0, a1, 0, 0, 0);
                a0 = __builtin_amdgcn_mfma_f32_16x16x32_bf16(wL1[0][1], x1, a0, 0, 0, 0);
                a1 = __builtin_amdgcn_mfma_f32_16x16x32_bf16(wL1[1][1], x1, a1, 0, 0, 0);
                a0 = __builtin_amdgcn_mfma_f32_16x16x32_bf16(wL1[0][2], x2, a0, 0, 0, 0);
                a1 = __builtin_amdgcn_mfma_f32_16x16x32_bf16(wL1[1][2], x2, a1, 0, 0, 0);
                ushort4v o0, o1;
                #pragma unroll
                for (int r = 0; r < 4; ++r) {
                    o0[r] = f2bf(fmaxf(a0[r] + bL1[0], 0.f));
                    o1[r] = f2bf(fmaxf(a1[r] + bL1[1], 0.f));
                }
                *(ushort4v*)(&sH1[c * XS + n12 + q * 4])      = o0;
                *(ushort4v*)(&sH1[c * XS + n12 + 16 + q * 4]) = o1;
            }
            __syncthreads();

            // ---- P2: L2 (H1 K=128 -> H2, relu); 2 N-tiles ----
            {
                const unsigned short* xb = &sH1[c * XS + q * 8];
                short8 x0 = *(const short8*)(xb);
                short8 x1 = *(const short8*)(xb + 32);
                short8 x2 = *(const short8*)(xb + 64);
                short8 x3 = *(const short8*)(xb + 96);
                f32x4 a0 = {0.f,0.f,0.f,0.f}, a1 = {0.f,0.f,0.f,0.f};
                a0 = __builtin_amdgcn_mfma_f32_16x16x32_bf16(wL2[0][0], x0, a0, 0, 0, 0);
                a1 = __builtin_amdgcn_mfma_f32_16x16x32_bf16(wL2[1][0], x0, a1, 0, 0, 0);
                a0 = __builtin_amdgcn_mfma_f32_16x16x32_bf16(wL2[0][1], x1, a0, 0, 0, 0);
                a1 = __builtin_amdgcn_mfma_f32_16x16x32_bf16(wL2[1][1], x1, a1, 0, 0, 0);
                a0 = __builtin_amdgcn_mfma_f32_16x16x32_bf16(wL2[0][2], x2, a0, 0, 0, 0);
                a1 = __builtin_amdgcn_mfma_f32_16x16x32_bf16(wL2[1][2], x2, a1, 0, 0, 0);
                a0 = __builtin_amdgcn_mfma_f32_16x16x32_bf16(wL2[0][3], x3, a0, 0, 0, 0);
                a1 = __builtin_amdgcn_mfma_f32_16x16x32_bf16(wL2[1][3], x3, a1, 0, 0, 0);
                ushort4v o0, o1;
                #pragma unroll
                for (int r = 0; r < 4; ++r) {
                    o0[r] = f2bf(fmaxf(a0[r] + bL2[0], 0.f));
                    o1[r] = f2bf(fmaxf(a1[r] + bL2[1], 0.f));
                }
                *(ushort4v*)(&sH2[c * XS + n12 + q * 4])      = o0;
                *(ushort4v*)(&sH2[c * XS + n12 + 16 + q * 4]) = o1;
            }
            __syncthreads();

            // ---- P3: L3 (H2 K=128 -> k_s) + fused state update + next-stage SI ----
            {
                const unsigned short* xb = &sH2[c * XS + q * 8];
                short8 x0 = *(const short8*)(xb);
                short8 x1 = *(const short8*)(xb + 32);
                short8 x2 = *(const short8*)(xb + 64);
                short8 x3 = *(const short8*)(xb + 96);
                f32x4 aa = {0.f,0.f,0.f,0.f}, ab = {0.f,0.f,0.f,0.f};
                aa = __builtin_amdgcn_mfma_f32_16x16x32_bf16(wL3[0], x0, aa, 0, 0, 0);
                ab = __builtin_amdgcn_mfma_f32_16x16x32_bf16(wL3[1], x1, ab, 0, 0, 0);
                aa = __builtin_amdgcn_mfma_f32_16x16x32_bf16(wL3[2], x2, aa, 0, 0, 0);
                ab = __builtin_amdgcn_mfma_f32_16x16x32_bf16(wL3[3], x3, ab, 0, 0, 0);
                aa = aa + ab;

                float kv[4];
                #pragma unroll
                for (int r = 0; r < 4; ++r) kv[r] = aa[r] + bL3;
                if      (s == 0) { k0[0]=kv[0]; k0[1]=kv[1]; k0[2]=kv[2]; k0[3]=kv[3]; }
                else if (s == 1) { k1[0]=kv[0]; k1[1]=kv[1]; k1[2]=kv[2]; k1[3]=kv[3]; }
                else if (s == 2) { k2[0]=kv[0]; k2[1]=kv[1]; k2[2]=kv[2]; k2[3]=kv[3]; }
                else if (s == 3) { k3[0]=kv[0]; k3[1]=kv[1]; k3[2]=kv[2]; k3[3]=kv[3]; }
                else if (s == 4) { k4[0]=kv[0]; k4[1]=kv[1]; k4[2]=kv[2]; k4[3]=kv[3]; }
                else             { k5[0]=kv[0]; k5[1]=kv[1]; k5[2]=kv[2]; k5[3]=kv[3]; }

                float si[4];
                if (s < 5) {
                    const float a0c = dA2[s + 1][0], a1c = dA2[s + 1][1], a2c = dA2[s + 1][2];
                    const float a3c = dA2[s + 1][3], a4c = dA2[s + 1][4], a5c = dA2[s + 1][5];
                    #pragma unroll
                    for (int r = 0; r < 4; ++r)
                        si[r] = sy[r] + dtv * (a0c*k0[r] + a1c*k1[r] + a2c*k2[r]
                                             + a3c*k3[r] + a4c*k4[r] + a5c*k5[r]);
                } else {
                    #pragma unroll
                    for (int r = 0; r < 4; ++r) {
                        sy[r] += dtv * (dB6v[0]*k0[r] + dB6v[1]*k1[r] + dB6v[2]*k2[r]
                                      + dB6v[3]*k3[r] + dB6v[4]*k4[r] + dB6v[5]*k5[r]);
                        si[r] = sy[r];
                    }
                }
                ushort4v ov;
                #pragma unroll
                for (int r = 0; r < 4; ++r) ov[r] = f2bf(si[r]);
                *(ushort4v*)(&sSI[c * XS + n3 + q * 4]) = ov;
                if (w == 0 && q == 0) {
                    const float tn = (s < 5) ? (tstep + dC6[s + 1] * dtv) : (tstep + dtv);
                    sSI[c * XS + 64] = f2bf(tn);
                }
            }
            __syncthreads();
        }
    }

    // ---- output: real batch rows are c<4 ----
    if (c < 4) {
        float4 v = make_float4(sy[0], sy[1], sy[2], sy[3]);
        *(float4*)(&out[(size_t)(row0 + c) * 64 + n3 + q * 4]) = v;
    }
}

extern "C" void kernel_launch(void* const* d_in, const int* in_sizes, int n_in,
                              void* d_out, int out_size, void* d_ws, size_t ws_size,
                              hipStream_t stream) {
    const float* y0 = (const float*)d_in[0];
    const float* ts = (const float*)d_in[1];
    const float* w0 = (const float*)d_in[2];
    const float* b0 = (const float*)d_in[3];
    const float* w1 = (const float*)d_in[4];
    const float* b1 = (const float*)d_in[5];
    const float* w2 = (const float*)d_in[6];
    const float* b2 = (const float*)d_in[7];
    float* out = (float*)d_out;

    node_solve<<<dim3(512), dim3(256), 0, stream>>>(y0, ts, w0, b0, w1, b1, w2, b2, out);
}

// Round 8
// 274.232 us; speedup vs baseline: 1.3987x; 1.3987x over previous
//
#include <hip/hip_runtime.h>

typedef __attribute__((ext_vector_type(8))) short short8;
typedef __attribute__((ext_vector_type(4))) float f32x4;
typedef __attribute__((ext_vector_type(4))) unsigned short ushort4v;

// dA2[sn][q] = coefficient of k_q in stage sn's input (zero-padded; row 0 unused)
__device__ __constant__ float dA2[6][6] = {
  {0.f, 0.f, 0.f, 0.f, 0.f, 0.f},
  {0.161f, 0.f, 0.f, 0.f, 0.f, 0.f},
  {-0.008480655492356989f, 0.335480655492357f, 0.f, 0.f, 0.f, 0.f},
  {2.8971530571054935f, -6.359448489975075f, 4.3622954328695815f, 0.f, 0.f, 0.f},
  {5.325864828439257f, -11.748883564062828f, 7.4955393428898365f, -0.09249506636175525f, 0.f, 0.f},
  {5.86145544294642f, -12.92096931784711f, 8.159367898576159f, -0.071584973281401f, -0.028269050394068383f, 0.f}
};
__device__ __constant__ float dC6[6] = {0.f, 0.161f, 0.327f, 0.9f, 0.9800255409045097f, 1.0f};
__device__ __constant__ float dB6v[6] = {0.09646076681806523f, 0.01f, 0.4798896504144996f,
                                         1.379008574103742f, -3.290069515436081f, 2.324710524099774f};

#define NSTEPS 49
#define XS 136   // bf16 activation row stride (272 B = 17*16): odd-17 16B groups, balanced banks

__device__ __forceinline__ unsigned short f2bf(float f) {
    unsigned u = __builtin_bit_cast(unsigned, f);
    u += 0x7fff + ((u >> 16) & 1);
    return (unsigned short)(u >> 16);
}

// 128 blocks x 256 thr (4 waves), M=16 batch rows/block — ALL 16 MFMA rows real.
// Per-block LDS traffic is ~constant in M, so M=16 halves chip LDS traffic and
// per-CU issue work vs M=8 (R6), quarter vs M=4 (R7). 1 block/CU on 128 CUs;
// ds_read latency exposed once per phase (reads batched before MFMAs).
// Transposed MFMA: C'[n][m] = W[n][k] X[m][k]; A = register weights, B = activations
// (b128 reads shared by the wave's two N-tiles); C' lane = 4 consecutive neurons of
// batch row c -> b64 epilogue writes. L1/L2: wave w owns cols [32w,32w+32);
// L3: cols [16w,16w+16), fused k/y state in registers. Stage loop fully unrolled:
// k-store branches and tableau indexing resolve at compile time.
extern "C" __global__ void __launch_bounds__(256, 1)
node_solve(const float* __restrict__ y0, const float* __restrict__ ts,
           const float* __restrict__ gw0, const float* __restrict__ gb0,
           const float* __restrict__ gw1, const float* __restrict__ gb1,
           const float* __restrict__ gw2, const float* __restrict__ gb2,
           float* __restrict__ out)
{
    __shared__ __align__(16) unsigned short sSI[16 * XS];  // [y' | t | zero pad], K-extent 96
    __shared__ __align__(16) unsigned short sH1[16 * XS];  // K=128
    __shared__ __align__(16) unsigned short sH2[16 * XS];  // K=128

    const int tid  = threadIdx.x;
    const int w    = tid >> 6;
    const int lane = tid & 63;
    const int q    = lane >> 4;
    const int c    = lane & 15;
    const int n12  = 32 * w;    // L1/L2 col base (2 tiles)
    const int n3   = 16 * w;    // L3 col base (1 tile)
    const int row0 = blockIdx.x * 16;

    // ---- zero SI cols 0..95 for all 16 rows (k-pad must be 0) ----
    for (int i = tid; i < 16 * 48; i += 256) {
        int r = i / 48, j = i - r * 48;
        ((int*)sSI)[r * 68 + j] = 0;
    }
    __syncthreads();
    // ---- init SI: rows 0..15 <- y0, time col 64 ----
    for (int i = tid; i < 16 * 64; i += 256) {
        int r = i >> 6, d = i & 63;
        sSI[r * XS + d] = f2bf(y0[(size_t)(row0 + r) * 64 + d]);
    }
    if (tid < 16) sSI[tid * XS + 64] = f2bf(ts[0]);

    // ---- weights -> register A-frags ----
    // L1 k-permutation: k<64 -> gw0 col 1+k (y_k); k==64 -> gw0 col 0 (t); k>64 -> 0
    short8 wL1[2][3], wL2[2][4], wL3[4];
    float  bL1[2], bL2[2], bL3;
    #pragma unroll
    for (int t = 0; t < 2; ++t) {
        const int n = n12 + 16 * t + c;
        #pragma unroll
        for (int ks = 0; ks < 3; ++ks) {
            short8 v;
            #pragma unroll
            for (int j = 0; j < 8; ++j) {
                const int k = ks * 32 + q * 8 + j;
                float f = (k < 64) ? gw0[n * 65 + 1 + k] : (k == 64 ? gw0[n * 65] : 0.f);
                v[j] = (short)f2bf(f);
            }
            wL1[t][ks] = v;
        }
        #pragma unroll
        for (int ks = 0; ks < 4; ++ks) {
            short8 v;
            #pragma unroll
            for (int j = 0; j < 8; ++j) v[j] = (short)f2bf(gw1[n * 128 + ks * 32 + q * 8 + j]);
            wL2[t][ks] = v;
        }
        bL1[t] = gb0[n]; bL2[t] = gb1[n];
    }
    {
        const int n = n3 + c;
        #pragma unroll
        for (int ks = 0; ks < 4; ++ks) {
            short8 v;
            #pragma unroll
            for (int j = 0; j < 8; ++j) v[j] = (short)f2bf(gw2[n * 128 + ks * 32 + q * 8 + j]);
            wL3[ks] = v;
        }
        bL3 = gb2[n];
    }

    // ---- persistent ODE state (all lanes real): batch row c, dims n3 + q*4 + r ----
    float sy[4];
    float k0[4], k1[4], k2[4], k3[4], k4[4], k5[4];
    #pragma unroll
    for (int r = 0; r < 4; ++r) { k0[r]=0.f; k1[r]=0.f; k2[r]=0.f; k3[r]=0.f; k4[r]=0.f; k5[r]=0.f; }
    #pragma unroll
    for (int r = 0; r < 4; ++r)
        sy[r] = y0[(size_t)(row0 + c) * 64 + n3 + q * 4 + r];

    const float ts0 = ts[0];
    const float dtv = ts[1] - ts[0];

    __syncthreads();

    #pragma unroll 1
    for (int step = 0; step < NSTEPS; ++step) {
        const float tstep = ts0 + (float)step * dtv;

        #pragma unroll
        for (int s = 0; s < 6; ++s) {
            // ---- P1: L1 (SI K=96 -> H1, relu); 2 N-tiles, shared B-frags ----
            {
                const unsigned short* xb = &sSI[c * XS + q * 8];
                short8 x0 = *(const short8*)(xb);
                short8 x1 = *(const short8*)(xb + 32);
                short8 x2 = *(const short8*)(xb + 64);
                f32x4 a0 = {0.f,0.f,0.f,0.f}, a1 = {0.f,0.f,0.f,0.f};
                a0 = __builtin_amdgcn_mfma_f32_16x16x32_bf16(wL1[0][0], x0, a0, 0, 0, 0);
                a1 = __builtin_amdgcn_mfma_f32_16x16x32_bf16(wL1[1][0], x0, a1, 0, 0, 0);
                a0 = __builtin_amdgcn_mfma_f32_16x16x32_bf16(wL1[0][1], x1, a0, 0, 0, 0);
                a1 = __builtin_amdgcn_mfma_f32_16x16x32_bf16(wL1[1][1], x1, a1, 0, 0, 0);
                a0 = __builtin_amdgcn_mfma_f32_16x16x32_bf16(wL1[0][2], x2, a0, 0, 0, 0);
                a1 = __builtin_amdgcn_mfma_f32_16x16x32_bf16(wL1[1][2], x2, a1, 0, 0, 0);
                ushort4v o0, o1;
                #pragma unroll
                for (int r = 0; r < 4; ++r) {
                    o0[r] = f2bf(fmaxf(a0[r] + bL1[0], 0.f));
                    o1[r] = f2bf(fmaxf(a1[r] + bL1[1], 0.f));
                }
                *(ushort4v*)(&sH1[c * XS + n12 + q * 4])      = o0;
                *(ushort4v*)(&sH1[c * XS + n12 + 16 + q * 4]) = o1;
            }
            __syncthreads();

            // ---- P2: L2 (H1 K=128 -> H2, relu); 2 N-tiles ----
            {
                const unsigned short* xb = &sH1[c * XS + q * 8];
                short8 x0 = *(const short8*)(xb);
                short8 x1 = *(const short8*)(xb + 32);
                short8 x2 = *(const short8*)(xb + 64);
                short8 x3 = *(const short8*)(xb + 96);
                f32x4 a0 = {0.f,0.f,0.f,0.f}, a1 = {0.f,0.f,0.f,0.f};
                a0 = __builtin_amdgcn_mfma_f32_16x16x32_bf16(wL2[0][0], x0, a0, 0, 0, 0);
                a1 = __builtin_amdgcn_mfma_f32_16x16x32_bf16(wL2[1][0], x0, a1, 0, 0, 0);
                a0 = __builtin_amdgcn_mfma_f32_16x16x32_bf16(wL2[0][1], x1, a0, 0, 0, 0);
                a1 = __builtin_amdgcn_mfma_f32_16x16x32_bf16(wL2[1][1], x1, a1, 0, 0, 0);
                a0 = __builtin_amdgcn_mfma_f32_16x16x32_bf16(wL2[0][2], x2, a0, 0, 0, 0);
                a1 = __builtin_amdgcn_mfma_f32_16x16x32_bf16(wL2[1][2], x2, a1, 0, 0, 0);
                a0 = __builtin_amdgcn_mfma_f32_16x16x32_bf16(wL2[0][3], x3, a0, 0, 0, 0);
                a1 = __builtin_amdgcn_mfma_f32_16x16x32_bf16(wL2[1][3], x3, a1, 0, 0, 0);
                ushort4v o0, o1;
                #pragma unroll
                for (int r = 0; r < 4; ++r) {
                    o0[r] = f2bf(fmaxf(a0[r] + bL2[0], 0.f));
                    o1[r] = f2bf(fmaxf(a1[r] + bL2[1], 0.f));
                }
                *(ushort4v*)(&sH2[c * XS + n12 + q * 4])      = o0;
                *(ushort4v*)(&sH2[c * XS + n12 + 16 + q * 4]) = o1;
            }
            __syncthreads();

            // ---- P3: L3 (H2 K=128 -> k_s) + fused state update + next-stage SI ----
            {
                const unsigned short* xb = &sH2[c * XS + q * 8];
                short8 x0 = *(const short8*)(xb);
                short8 x1 = *(const short8*)(xb + 32);
                short8 x2 = *(const short8*)(xb + 64);
                short8 x3 = *(const short8*)(xb + 96);
                f32x4 aa = {0.f,0.f,0.f,0.f}, ab = {0.f,0.f,0.f,0.f};
                aa = __builtin_amdgcn_mfma_f32_16x16x32_bf16(wL3[0], x0, aa, 0, 0, 0);
                ab = __builtin_amdgcn_mfma_f32_16x16x32_bf16(wL3[1], x1, ab, 0, 0, 0);
                aa = __builtin_amdgcn_mfma_f32_16x16x32_bf16(wL3[2], x2, aa, 0, 0, 0);
                ab = __builtin_amdgcn_mfma_f32_16x16x32_bf16(wL3[3], x3, ab, 0, 0, 0);
                aa = aa + ab;

                float kv[4];
                #pragma unroll
                for (int r = 0; r < 4; ++r) kv[r] = aa[r] + bL3;
                // s is compile-time (unrolled): direct register assignment
                if      (s == 0) { k0[0]=kv[0]; k0[1]=kv[1]; k0[2]=kv[2]; k0[3]=kv[3]; }
                else if (s == 1) { k1[0]=kv[0]; k1[1]=kv[1]; k1[2]=kv[2]; k1[3]=kv[3]; }
                else if (s == 2) { k2[0]=kv[0]; k2[1]=kv[1]; k2[2]=kv[2]; k2[3]=kv[3]; }
                else if (s == 3) { k3[0]=kv[0]; k3[1]=kv[1]; k3[2]=kv[2]; k3[3]=kv[3]; }
                else if (s == 4) { k4[0]=kv[0]; k4[1]=kv[1]; k4[2]=kv[2]; k4[3]=kv[3]; }
                else             { k5[0]=kv[0]; k5[1]=kv[1]; k5[2]=kv[2]; k5[3]=kv[3]; }

                float si[4];
                if (s < 5) {
                    const float a0c = dA2[s + 1][0], a1c = dA2[s + 1][1], a2c = dA2[s + 1][2];
                    const float a3c = dA2[s + 1][3], a4c = dA2[s + 1][4], a5c = dA2[s + 1][5];
                    #pragma unroll
                    for (int r = 0; r < 4; ++r)
                        si[r] = sy[r] + dtv * (a0c*k0[r] + a1c*k1[r] + a2c*k2[r]
                                             + a3c*k3[r] + a4c*k4[r] + a5c*k5[r]);
                } else {
                    #pragma unroll
                    for (int r = 0; r < 4; ++r) {
                        sy[r] += dtv * (dB6v[0]*k0[r] + dB6v[1]*k1[r] + dB6v[2]*k2[r]
                                      + dB6v[3]*k3[r] + dB6v[4]*k4[r] + dB6v[5]*k5[r]);
                        si[r] = sy[r];
                    }
                }
                ushort4v ov;
                #pragma unroll
                for (int r = 0; r < 4; ++r) ov[r] = f2bf(si[r]);
                *(ushort4v*)(&sSI[c * XS + n3 + q * 4]) = ov;
                if (w == 0 && q == 0) {
                    const float tn = (s < 5) ? (tstep + dC6[s + 1] * dtv) : (tstep + dtv);
                    sSI[c * XS + 64] = f2bf(tn);
                }
            }
            __syncthreads();
        }
    }

    // ---- output: all lanes hold real state ----
    {
        float4 v = make_float4(sy[0], sy[1], sy[2], sy[3]);
        *(float4*)(&out[(size_t)(row0 + c) * 64 + n3 + q * 4]) = v;
    }
}

extern "C" void kernel_launch(void* const* d_in, const int* in_sizes, int n_in,
                              void* d_out, int out_size, void* d_ws, size_t ws_size,
                              hipStream_t stream) {
    const float* y0 = (const float*)d_in[0];
    const float* ts = (const float*)d_in[1];
    const float* w0 = (const float*)d_in[2];
    const float* b0 = (const float*)d_in[3];
    const float* w1 = (const float*)d_in[4];
    const float* b1 = (const float*)d_in[5];
    const float* w2 = (const float*)d_in[6];
    const float* b2 = (const float*)d_in[7];
    float* out = (float*)d_out;

    node_solve<<<dim3(128), dim3(256), 0, stream>>>(y0, ts, w0, b0, w1, b1, w2, b2, out);
}

// Round 9
// 252.983 us; speedup vs baseline: 1.5162x; 1.0840x over previous
//
#include <hip/hip_runtime.h>

typedef __attribute__((ext_vector_type(8))) short short8;
typedef __attribute__((ext_vector_type(4))) float f32x4;
typedef __attribute__((ext_vector_type(4))) unsigned short ushort4v;

// dA2[sn][q] = coefficient of k_q in stage sn's input (zero-padded; row 0 unused)
__device__ __constant__ float dA2[6][6] = {
  {0.f, 0.f, 0.f, 0.f, 0.f, 0.f},
  {0.161f, 0.f, 0.f, 0.f, 0.f, 0.f},
  {-0.008480655492356989f, 0.335480655492357f, 0.f, 0.f, 0.f, 0.f},
  {2.8971530571054935f, -6.359448489975075f, 4.3622954328695815f, 0.f, 0.f, 0.f},
  {5.325864828439257f, -11.748883564062828f, 7.4955393428898365f, -0.09249506636175525f, 0.f, 0.f},
  {5.86145544294642f, -12.92096931784711f, 8.159367898576159f, -0.071584973281401f, -0.028269050394068383f, 0.f}
};
__device__ __constant__ float dC6[6] = {0.f, 0.161f, 0.327f, 0.9f, 0.9800255409045097f, 1.0f};
__device__ __constant__ float dB6v[6] = {0.09646076681806523f, 0.01f, 0.4798896504144996f,
                                         1.379008574103742f, -3.290069515436081f, 2.324710524099774f};

#define NSTEPS 49
#define XS 136   // bf16 activation row stride (272 B = 17*16)

__device__ __forceinline__ unsigned short f2bf(float f) {
    unsigned u = __builtin_bit_cast(unsigned, f);
    u += 0x7fff + ((u >> 16) & 1);
    return (unsigned short)(u >> 16);
}

// 128 blocks x 512 thr (8 waves = 2/SIMD), M=16 batch rows/block (all MFMA rows real).
// R8 (4 waves, 1/SIMD) was latency-chain-bound: 1788 cyc/stage vs ~900 cyc issue work.
// 8 waves give every SIMD two independent same-phase waves whose ds_read/MFMA/epilogue
// chains interleave. Per-CU MFMA count unchanged (72/stage); LDS reads 44->72 b128.
// L1/L2: wave w owns ONE 16-col tile (cols 16w..16w+15). L3: waves 0-3 own 4 tiles,
// fused ODE state (k1..k6, y) in their lanes; waves 4-7 idle through P3 (shortest phase).
// Transposed MFMA: C'[n][m] = W[n][k] X[m][k]; A = register weights, B = activation
// b128 reads; C' lane = 4 consecutive neurons of batch row c -> b64 epilogue writes.
extern "C" __global__ void __launch_bounds__(512, 1)
node_solve(const float* __restrict__ y0, const float* __restrict__ ts,
           const float* __restrict__ gw0, const float* __restrict__ gb0,
           const float* __restrict__ gw1, const float* __restrict__ gb1,
           const float* __restrict__ gw2, const float* __restrict__ gb2,
           float* __restrict__ out)
{
    __shared__ __align__(16) unsigned short sSI[16 * XS];  // [y' | t | zero pad], K-extent 96
    __shared__ __align__(16) unsigned short sH1[16 * XS];  // K=128
    __shared__ __align__(16) unsigned short sH2[16 * XS];  // K=128

    const int tid  = threadIdx.x;
    const int w    = tid >> 6;      // wave 0..7
    const int lane = tid & 63;
    const int q    = lane >> 4;
    const int c    = lane & 15;
    const int nt   = 16 * w;        // L1/L2 col base (1 tile per wave)
    const int n3   = 16 * w;        // L3 col base (waves 0..3)
    const int row0 = blockIdx.x * 16;

    // ---- zero SI cols 0..95 for all 16 rows (k-pad must be 0) ----
    for (int i = tid; i < 16 * 48; i += 512) {
        int r = i / 48, j = i - r * 48;
        ((int*)sSI)[r * 68 + j] = 0;
    }
    __syncthreads();
    // ---- init SI: rows 0..15 <- y0, time col 64 ----
    for (int i = tid; i < 16 * 64; i += 512) {
        int r = i >> 6, d = i & 63;
        sSI[r * XS + d] = f2bf(y0[(size_t)(row0 + r) * 64 + d]);
    }
    if (tid < 16) sSI[tid * XS + 64] = f2bf(ts[0]);

    // ---- weights -> register A-frags (1 L1 tile + 1 L2 tile per wave) ----
    // L1 k-permutation: k<64 -> gw0 col 1+k (y_k); k==64 -> gw0 col 0 (t); k>64 -> 0
    short8 wL1[3], wL2[4], wL3[4];
    float  bL1, bL2, bL3 = 0.f;
    {
        const int n = nt + c;
        #pragma unroll
        for (int ks = 0; ks < 3; ++ks) {
            short8 v;
            #pragma unroll
            for (int j = 0; j < 8; ++j) {
                const int k = ks * 32 + q * 8 + j;
                float f = (k < 64) ? gw0[n * 65 + 1 + k] : (k == 64 ? gw0[n * 65] : 0.f);
                v[j] = (short)f2bf(f);
            }
            wL1[ks] = v;
        }
        #pragma unroll
        for (int ks = 0; ks < 4; ++ks) {
            short8 v;
            #pragma unroll
            for (int j = 0; j < 8; ++j) v[j] = (short)f2bf(gw1[n * 128 + ks * 32 + q * 8 + j]);
            wL2[ks] = v;
        }
        bL1 = gb0[n]; bL2 = gb1[n];
    }
    if (w < 4) {
        const int n = n3 + c;
        #pragma unroll
        for (int ks = 0; ks < 4; ++ks) {
            short8 v;
            #pragma unroll
            for (int j = 0; j < 8; ++j) v[j] = (short)f2bf(gw2[n * 128 + ks * 32 + q * 8 + j]);
            wL3[ks] = v;
        }
        bL3 = gb2[n];
    }

    // ---- persistent ODE state (waves 0..3): batch row c, dims n3 + q*4 + r ----
    float sy[4] = {0.f, 0.f, 0.f, 0.f};
    float k0[4], k1[4], k2[4], k3[4], k4[4], k5[4];
    #pragma unroll
    for (int r = 0; r < 4; ++r) { k0[r]=0.f; k1[r]=0.f; k2[r]=0.f; k3[r]=0.f; k4[r]=0.f; k5[r]=0.f; }
    if (w < 4) {
        #pragma unroll
        for (int r = 0; r < 4; ++r)
            sy[r] = y0[(size_t)(row0 + c) * 64 + n3 + q * 4 + r];
    }

    const float ts0 = ts[0];
    const float dtv = ts[1] - ts[0];

    __syncthreads();

    #pragma unroll 1
    for (int step = 0; step < NSTEPS; ++step) {
        const float tstep = ts0 + (float)step * dtv;

        #pragma unroll
        for (int s = 0; s < 6; ++s) {
            // ---- P1: L1 (SI K=96 -> H1, relu); one tile per wave ----
            {
                const unsigned short* xb = &sSI[c * XS + q * 8];
                short8 x0 = *(const short8*)(xb);
                short8 x1 = *(const short8*)(xb + 32);
                short8 x2 = *(const short8*)(xb + 64);
                f32x4 a0 = {0.f,0.f,0.f,0.f};
                a0 = __builtin_amdgcn_mfma_f32_16x16x32_bf16(wL1[0], x0, a0, 0, 0, 0);
                a0 = __builtin_amdgcn_mfma_f32_16x16x32_bf16(wL1[1], x1, a0, 0, 0, 0);
                a0 = __builtin_amdgcn_mfma_f32_16x16x32_bf16(wL1[2], x2, a0, 0, 0, 0);
                ushort4v o0;
                #pragma unroll
                for (int r = 0; r < 4; ++r) o0[r] = f2bf(fmaxf(a0[r] + bL1, 0.f));
                *(ushort4v*)(&sH1[c * XS + nt + q * 4]) = o0;
            }
            __syncthreads();

            // ---- P2: L2 (H1 K=128 -> H2, relu); one tile per wave ----
            {
                const unsigned short* xb = &sH1[c * XS + q * 8];
                short8 x0 = *(const short8*)(xb);
                short8 x1 = *(const short8*)(xb + 32);
                short8 x2 = *(const short8*)(xb + 64);
                short8 x3 = *(const short8*)(xb + 96);
                f32x4 a0 = {0.f,0.f,0.f,0.f}, a1 = {0.f,0.f,0.f,0.f};
                a0 = __builtin_amdgcn_mfma_f32_16x16x32_bf16(wL2[0], x0, a0, 0, 0, 0);
                a1 = __builtin_amdgcn_mfma_f32_16x16x32_bf16(wL2[1], x1, a1, 0, 0, 0);
                a0 = __builtin_amdgcn_mfma_f32_16x16x32_bf16(wL2[2], x2, a0, 0, 0, 0);
                a1 = __builtin_amdgcn_mfma_f32_16x16x32_bf16(wL2[3], x3, a1, 0, 0, 0);
                a0 = a0 + a1;
                ushort4v o0;
                #pragma unroll
                for (int r = 0; r < 4; ++r) o0[r] = f2bf(fmaxf(a0[r] + bL2, 0.f));
                *(ushort4v*)(&sH2[c * XS + nt + q * 4]) = o0;
            }
            __syncthreads();

            // ---- P3: L3 (H2 K=128 -> k_s) + fused state update + next-stage SI ----
            if (w < 4) {
                const unsigned short* xb = &sH2[c * XS + q * 8];
                short8 x0 = *(const short8*)(xb);
                short8 x1 = *(const short8*)(xb + 32);
                short8 x2 = *(const short8*)(xb + 64);
                short8 x3 = *(const short8*)(xb + 96);
                f32x4 aa = {0.f,0.f,0.f,0.f}, ab = {0.f,0.f,0.f,0.f};
                aa = __builtin_amdgcn_mfma_f32_16x16x32_bf16(wL3[0], x0, aa, 0, 0, 0);
                ab = __builtin_amdgcn_mfma_f32_16x16x32_bf16(wL3[1], x1, ab, 0, 0, 0);
                aa = __builtin_amdgcn_mfma_f32_16x16x32_bf16(wL3[2], x2, aa, 0, 0, 0);
                ab = __builtin_amdgcn_mfma_f32_16x16x32_bf16(wL3[3], x3, ab, 0, 0, 0);
                aa = aa + ab;

                float kv[4];
                #pragma unroll
                for (int r = 0; r < 4; ++r) kv[r] = aa[r] + bL3;
                // s is compile-time (unrolled): direct register assignment
                if      (s == 0) { k0[0]=kv[0]; k0[1]=kv[1]; k0[2]=kv[2]; k0[3]=kv[3]; }
                else if (s == 1) { k1[0]=kv[0]; k1[1]=kv[1]; k1[2]=kv[2]; k1[3]=kv[3]; }
                else if (s == 2) { k2[0]=kv[0]; k2[1]=kv[1]; k2[2]=kv[2]; k2[3]=kv[3]; }
                else if (s == 3) { k3[0]=kv[0]; k3[1]=kv[1]; k3[2]=kv[2]; k3[3]=kv[3]; }
                else if (s == 4) { k4[0]=kv[0]; k4[1]=kv[1]; k4[2]=kv[2]; k4[3]=kv[3]; }
                else             { k5[0]=kv[0]; k5[1]=kv[1]; k5[2]=kv[2]; k5[3]=kv[3]; }

                float si[4];
                if (s < 5) {
                    const float a0c = dA2[s + 1][0], a1c = dA2[s + 1][1], a2c = dA2[s + 1][2];
                    const float a3c = dA2[s + 1][3], a4c = dA2[s + 1][4], a5c = dA2[s + 1][5];
                    #pragma unroll
                    for (int r = 0; r < 4; ++r)
                        si[r] = sy[r] + dtv * (a0c*k0[r] + a1c*k1[r] + a2c*k2[r]
                                             + a3c*k3[r] + a4c*k4[r] + a5c*k5[r]);
                } else {
                    #pragma unroll
                    for (int r = 0; r < 4; ++r) {
                        sy[r] += dtv * (dB6v[0]*k0[r] + dB6v[1]*k1[r] + dB6v[2]*k2[r]
                                      + dB6v[3]*k3[r] + dB6v[4]*k4[r] + dB6v[5]*k5[r]);
                        si[r] = sy[r];
                    }
                }
                ushort4v ov;
                #pragma unroll
                for (int r = 0; r < 4; ++r) ov[r] = f2bf(si[r]);
                *(ushort4v*)(&sSI[c * XS + n3 + q * 4]) = ov;
                if (w == 0 && q == 0) {
                    const float tn = (s < 5) ? (tstep + dC6[s + 1] * dtv) : (tstep + dtv);
                    sSI[c * XS + 64] = f2bf(tn);
                }
            }
            __syncthreads();
        }
    }

    // ---- output: waves 0..3 hold the state ----
    if (w < 4) {
        float4 v = make_float4(sy[0], sy[1], sy[2], sy[3]);
        *(float4*)(&out[(size_t)(row0 + c) * 64 + n3 + q * 4]) = v;
    }
}

extern "C" void kernel_launch(void* const* d_in, const int* in_sizes, int n_in,
                              void* d_out, int out_size, void* d_ws, size_t ws_size,
                              hipStream_t stream) {
    const float* y0 = (const float*)d_in[0];
    const float* ts = (const float*)d_in[1];
    const float* w0 = (const float*)d_in[2];
    const float* b0 = (const float*)d_in[3];
    const float* w1 = (const float*)d_in[4];
    const float* b1 = (const float*)d_in[5];
    const float* w2 = (const float*)d_in[6];
    const float* b2 = (const float*)d_in[7];
    float* out = (float*)d_out;

    node_solve<<<dim3(128), dim3(512), 0, stream>>>(y0, ts, w0, b0, w1, b1, w2, b2, out);
}